// Round 2
// baseline (3843.081 us; speedup 1.0000x reference)
//
#include <hip/hip_runtime.h>

// Problem constants (from reference)
#define TT   64
#define BB   2048
#define IND  512
#define HH   1024
#define G3   3072
#define TBM  (TT*BB)   // 131072 total rows

typedef short  short8 __attribute__((ext_vector_type(8)));
typedef float  f32x4  __attribute__((ext_vector_type(4)));

__device__ __forceinline__ unsigned short f2bf(float x) {
  unsigned int u = __float_as_uint(x);
  u += 0x7FFFu + ((u >> 16) & 1u);           // RNE
  return (unsigned short)(u >> 16);
}
__device__ __forceinline__ float bf2f(unsigned short u) {
  return __uint_as_float(((unsigned int)u) << 16);
}

// async global->LDS, 16B per lane. LDS dest = wave-uniform base + lane*16.
__device__ __forceinline__ void async16(const void* g, void* l) {
  __builtin_amdgcn_global_load_lds(
      (__attribute__((address_space(1))) void*)(void*)g,
      (__attribute__((address_space(3))) void*)l, 16, 0, 0);
}

// ---------------- cast fp32 -> bf16 (vectorized, grid-stride) ----------------
__global__ void cast_bf16_kernel(const float* __restrict__ src,
                                 unsigned short* __restrict__ dst, int n) {
  int stride = gridDim.x * blockDim.x;
  for (int i = blockIdx.x * blockDim.x + threadIdx.x; i * 8 < n; i += stride) {
    int o = i * 8;
    float4 a = *(const float4*)(src + o);
    float4 b = *(const float4*)(src + o + 4);
    ushort4 lo; lo.x = f2bf(a.x); lo.y = f2bf(a.y); lo.z = f2bf(a.z); lo.w = f2bf(a.w);
    ushort4 hi; hi.x = f2bf(b.x); hi.y = f2bf(b.y); hi.z = f2bf(b.z); hi.w = f2bf(b.w);
    *(ushort4*)(dst + o)     = lo;
    *(ushort4*)(dst + o + 4) = hi;
  }
}

// ---------------- init output with b3 ----------------
__global__ void init_out_kernel(float* __restrict__ out, const float* __restrict__ b3, int n) {
  float v = b3[0];
  for (int i = blockIdx.x * blockDim.x + threadIdx.x; i < n; i += gridDim.x * blockDim.x)
    out[i] = v;
}

// ---------------- bf16 GEMM: C[M][N] = act(A[M][K] * Bw[N][K]^T + bias) ------
// m97 structure: 128x128 tile, BK=32, 4 waves (2x2), global_load_lds w=16,
// mfma_f32_16x16x32_bf16 with contiguous-8 operand layout.
template <int RELU>
__global__ __launch_bounds__(256, 2) void gemm_bf16(
    const unsigned short* __restrict__ A,   // [M][K] bf16
    const unsigned short* __restrict__ Bw,  // [N][K] bf16
    const float* __restrict__ bias,         // [N]
    unsigned short* __restrict__ C,         // [M][N] bf16
    int M, int N, int K) {
  __shared__ __align__(16) unsigned short As[128 * 32];
  __shared__ __align__(16) unsigned short Bs[128 * 32];
  const int tid = threadIdx.x;
  const int w = tid >> 6, l = tid & 63;
  const int wr = w >> 1, wc = w & 1;
  const int lq = l >> 4, lr = l & 15;
  const long m0 = (long)blockIdx.y * 128;
  const int  n0 = blockIdx.x * 128;
  const int srow = l >> 2, scol = (l & 3) * 8;

  f32x4 acc[4][4] = {};

  const unsigned short* ga = A  + (m0 + w * 32 + srow) * K + scol;
  const unsigned short* gb = Bw + (long)(n0 + w * 32 + srow) * K + scol;
  unsigned short* lA = &As[(w * 32) * 32];
  unsigned short* lB = &Bs[(w * 32) * 32];

  for (int k0 = 0; k0 < K; k0 += 32) {
    async16(ga,          lA);
    async16(ga + 16 * K, lA + 16 * 32);
    async16(gb,          lB);
    async16(gb + 16 * K, lB + 16 * 32);
    ga += 32; gb += 32;
    __syncthreads();
    short8 af[4], bfv[4];
#pragma unroll
    for (int mf = 0; mf < 4; mf++)
      af[mf] = *(const short8*)&As[(wr * 64 + mf * 16 + lr) * 32 + 8 * lq];
#pragma unroll
    for (int nf = 0; nf < 4; nf++)
      bfv[nf] = *(const short8*)&Bs[(wc * 64 + nf * 16 + lr) * 32 + 8 * lq];
#pragma unroll
    for (int mf = 0; mf < 4; mf++)
#pragma unroll
      for (int nf = 0; nf < 4; nf++)
        acc[mf][nf] = __builtin_amdgcn_mfma_f32_16x16x32_bf16(af[mf], bfv[nf], acc[mf][nf], 0, 0, 0);
    __syncthreads();
  }

#pragma unroll
  for (int nf = 0; nf < 4; nf++) {
    int col = n0 + wc * 64 + nf * 16 + lr;
    float bv = bias[col];
#pragma unroll
    for (int mf = 0; mf < 4; mf++) {
      long row = m0 + wr * 64 + mf * 16 + 4 * lq;
#pragma unroll
      for (int r = 0; r < 4; r++) {
        float v = acc[mf][nf][r] + bv;
        if (RELU) v = fmaxf(v, 0.f);
        C[(row + r) * N + col] = f2bf(v);
      }
    }
  }
}

// ---------------- fused GRU step ----------------
// gh = h_prev @ W_hh^T (+b_hh), gates, h update, q = h_new . W3 (atomicAdd)
// Tile: BM=64 x BN=64(h-cols) x 3 gates, 4 waves (2x2), BK=32.
__global__ __launch_bounds__(256, 2) void gru_step(
    const unsigned short* __restrict__ hprev_bf, // [BB][HH] bf16
    const float* __restrict__ hprev_f,           // [BB][HH] f32
    float* __restrict__ hnext_f,                 // [BB][HH] f32
    unsigned short* __restrict__ hnext_bf,       // [BB][HH] bf16
    const unsigned short* __restrict__ Whh,      // [3H][H] bf16
    const unsigned short* __restrict__ gx,       // [TC*B][3H] bf16, chunk-local
    const float* __restrict__ bhh,               // [3H]
    const float* __restrict__ W3,                // [H]
    float* __restrict__ out,                     // [T*B] (pre-init to b3)
    int lt, int t) {
  __shared__ __align__(16) unsigned short As[64 * 32];
  __shared__ __align__(16) unsigned short Bs[3][64 * 32];
  const int tid = threadIdx.x;
  const int w = tid >> 6, l = tid & 63;
  const int wr = w >> 1, wc = w & 1;
  const int lq = l >> 4, lr = l & 15;
  const int m0 = blockIdx.y * 64;   // batch rows
  const int n0 = blockIdx.x * 64;   // h cols
  const int srow = l >> 2, scol = (l & 3) * 8;

  f32x4 acc[3][2][2] = {};

  const unsigned short* ga = hprev_bf + (m0 + w * 16 + srow) * HH + scol;
  unsigned short* lA = &As[(w * 16) * 32];

  for (int k0 = 0; k0 < HH; k0 += 32) {
    async16(ga, lA);
#pragma unroll
    for (int g = 0; g < 3; g++) {
      const unsigned short* gb =
          Whh + (long)(g * HH + n0 + w * 16 + srow) * HH + k0 + scol;
      async16(gb, &Bs[g][(w * 16) * 32]);
    }
    ga += 32;
    __syncthreads();
    short8 af[2];
#pragma unroll
    for (int mf = 0; mf < 2; mf++)
      af[mf] = *(const short8*)&As[(wr * 32 + mf * 16 + lr) * 32 + 8 * lq];
#pragma unroll
    for (int g = 0; g < 3; g++)
#pragma unroll
      for (int nf = 0; nf < 2; nf++) {
        short8 bfr = *(const short8*)&Bs[g][(wc * 32 + nf * 16 + lr) * 32 + 8 * lq];
#pragma unroll
        for (int mf = 0; mf < 2; mf++)
          acc[g][mf][nf] = __builtin_amdgcn_mfma_f32_16x16x32_bf16(af[mf], bfr, acc[g][mf][nf], 0, 0, 0);
      }
    __syncthreads();
  }

  // epilogue: gates + h update + q partials
  float qp[2][4] = {};
#pragma unroll
  for (int nf = 0; nf < 2; nf++) {
    int n = n0 + wc * 32 + nf * 16 + lr;
    float bhr = bhh[n], bhz = bhh[HH + n], bhn = bhh[2 * HH + n];
    float w3v = W3[n];
#pragma unroll
    for (int mf = 0; mf < 2; mf++) {
      int mrow = m0 + wr * 32 + mf * 16 + 4 * lq;
#pragma unroll
      for (int r = 0; r < 4; r++) {
        int m = mrow + r;
        long gxb = ((long)lt * BB + m) * G3 + n;
        float xr = bf2f(gx[gxb]);
        float xz = bf2f(gx[gxb + HH]);
        float xn = bf2f(gx[gxb + 2 * HH]);
        float ghr = acc[0][mf][nf][r] + bhr;
        float ghz = acc[1][mf][nf][r] + bhz;
        float ghn = acc[2][mf][nf][r] + bhn;
        float rg = 1.f / (1.f + __expf(-(xr + ghr)));
        float zg = 1.f / (1.f + __expf(-(xz + ghz)));
        float ng = tanhf(xn + rg * ghn);
        float hp = hprev_f[(long)m * HH + n];
        float hv = (1.f - zg) * ng + zg * hp;
        hnext_f[(long)m * HH + n] = hv;
        hnext_bf[(long)m * HH + n] = f2bf(hv);
        qp[mf][r] += hv * w3v;
      }
    }
  }
  // reduce q partials over the 16 lanes (lr) of each quarter-group, then atomicAdd
#pragma unroll
  for (int mf = 0; mf < 2; mf++)
#pragma unroll
    for (int r = 0; r < 4; r++) {
      float v = qp[mf][r];
      v += __shfl_xor(v, 1);
      v += __shfl_xor(v, 2);
      v += __shfl_xor(v, 4);
      v += __shfl_xor(v, 8);
      if (lr == 0) {
        int m = m0 + wr * 32 + mf * 16 + 4 * lq + r;
        atomicAdd(&out[t * BB + m], v);
      }
    }
}

// ---------------- host ----------------
extern "C" void kernel_launch(void* const* d_in, const int* in_sizes, int n_in,
                              void* d_out, int out_size, void* d_ws, size_t ws_size,
                              hipStream_t stream) {
  const float* inputs = (const float*)d_in[0];
  const float* W1     = (const float*)d_in[1];
  const float* b1     = (const float*)d_in[2];
  const float* W_ih   = (const float*)d_in[3];
  const float* b_ih   = (const float*)d_in[4];
  const float* W_hh   = (const float*)d_in[5];
  const float* b_hh   = (const float*)d_in[6];
  const float* W3     = (const float*)d_in[7];
  const float* b3     = (const float*)d_in[8];
  float* out = (float*)d_out;

  // ---- adaptive workspace layout (ws_size is constant across calls ->
  //      identical work every call, graph-safe) ----
  // fixed: whhb 6,291,456 | wihb 6,291,456 | w1b 1,048,576
  //        hf0/hf1 2x 8,388,608 | hb0/hb1 2x 4,194,304   = 38,797,312 B
  // per-chunk (TC timesteps): gxc TC*12,582,912 | xc TC*4,194,304 |
  //        inbfc TC*2,097,152                             = TC*18,874,368 B
  const long FIXED = 38797312L;
  const long PER   = 18874368L;
  int TC = 64;
  while (TC > 1 && FIXED + (long)TC * PER > (long)ws_size) TC >>= 1;

  char* ws = (char*)d_ws;
  unsigned short* whhb = (unsigned short*)ws;
  unsigned short* wihb = whhb + 3145728;
  unsigned short* w1b  = wihb + 3145728;
  float* hf0 = (float*)(ws + 13631488L);
  float* hf1 = hf0 + (long)BB * HH;
  unsigned short* hb0 = (unsigned short*)(ws + 30408704L);
  unsigned short* hb1 = hb0 + (long)BB * HH;
  unsigned short* gxc   = (unsigned short*)(ws + FIXED);
  unsigned short* xc    = gxc + (long)TC * BB * G3;
  unsigned short* inbfc = xc  + (long)TC * BB * HH;

  // weight casts + h0 init + out=b3 (once)
  cast_bf16_kernel<<<512, 256, 0, stream>>>(W1,   w1b,  HH * IND);
  cast_bf16_kernel<<<1024, 256, 0, stream>>>(W_ih, wihb, G3 * HH);
  cast_bf16_kernel<<<1024, 256, 0, stream>>>(W_hh, whhb, G3 * HH);
  hipMemsetAsync(hf0, 0, (long)BB * HH * 4, stream);
  hipMemsetAsync(hb0, 0, (long)BB * HH * 2, stream);
  init_out_kernel<<<512, 256, 0, stream>>>(out, b3, TBM);

  for (int c = 0; c < TT; c += TC) {
    const int rows = TC * BB;  // chunk rows
    // cast input slice
    cast_bf16_kernel<<<2048, 256, 0, stream>>>(
        inputs + (long)c * BB * IND, inbfc, rows * IND);
    // xc = relu(in @ W1^T + b1)
    gemm_bf16<1><<<dim3(HH / 128, rows / 128), 256, 0, stream>>>(
        inbfc, w1b, b1, xc, rows, HH, IND);
    // gxc = xc @ W_ih^T + b_ih
    gemm_bf16<0><<<dim3(G3 / 128, rows / 128), 256, 0, stream>>>(
        xc, wihb, b_ih, gxc, rows, G3, HH);
    // serial GRU steps for this chunk
    for (int lt = 0; lt < TC; lt++) {
      const int t = c + lt;
      const unsigned short* hbr = (t & 1) ? hb1 : hb0;
      const float*          hfr = (t & 1) ? hf1 : hf0;
      float*                hfw = (t & 1) ? hf0 : hf1;
      unsigned short*       hbw = (t & 1) ? hb0 : hb1;
      gru_step<<<dim3(HH / 64, BB / 64), 256, 0, stream>>>(
          hbr, hfr, hfw, hbw, whhb, gxc, b_hh, W3, out, lt, t);
    }
  }
}